// Round 3
// baseline (223.571 us; speedup 1.0000x reference)
//
#include <hip/hip_runtime.h>
#include <stdint.h>

// ---------------------------------------------------------------------------
// BertSelfAttention (relative_key_query) on gfx950.
// B=4 S=1024 H=768 nH=12 dH=64 MAXPOS=1024.
//   q,k,v = hidden @ W{q,k,v}.T + b        (bf16 MFMA GEMM)
//   S[l,r] = q.k + q.E[l-r+1023] + k.E[l-r+1023];  softmax(S/8 + mask) @ v
// Pipeline: convert(fp32->bf16) -> qkv_gemm -> fused flash attention.
// v4 attn = v3 datapath minus the register squeeze:
//   - launch_bounds (256,2): no forced 84/84 VGPR/AGPR split -> no scratch
//     spills (v3's +18.6MB WRITE_SIZE). LDS 48.5KB still allows 3 blocks/CU
//     if regalloc lands <=~170 total.
//   - E frags batched 3+2 (peak E-regs 32 not 40), batch2 issued mid-loop so
//     L2 latency hides under Qe/Ke MFMAs.
//   - qe[5] acc array eliminated: each Qe tile computes -> stores immediately.
// ---------------------------------------------------------------------------

typedef __attribute__((ext_vector_type(4))) float f32x4;
typedef __attribute__((ext_vector_type(8))) short s16x8;
typedef const __attribute__((address_space(1))) void GCV;
typedef __attribute__((address_space(3))) void LDSV;

__device__ __forceinline__ unsigned short f2bf(float f) {
  union { float f; uint32_t u; } v; v.f = f;
  uint32_t r = (v.u + 0x7FFFu + ((v.u >> 16) & 1u)) >> 16;
  return (unsigned short)r;
}
__device__ __forceinline__ float bf2f(unsigned short b) {
  union { uint32_t u; float f; } v; v.u = ((uint32_t)b) << 16;
  return v.f;
}

#define MFMA(a, b, c) __builtin_amdgcn_mfma_f32_16x16x32_bf16((a), (b), (c), 0, 0, 0)

// ---------------------------------------------------------------------------
// Kernel 0: fp32 -> bf16 conversion. hidden [4096x768], Wq|Wk|Wv [768x768]x3,
// dist_emb [2047x64] padded to 2048 rows (row 2047 = 0).
// ---------------------------------------------------------------------------
#define HIDQ 786432   // 4096*768/4
#define WQ4  147456   // 768*768/4
#define EQ4  32768    // 2048*64/4

__global__ __launch_bounds__(256) void convert_kernel(
    const float* __restrict__ hid, const float* __restrict__ wq,
    const float* __restrict__ wk, const float* __restrict__ wv,
    const float* __restrict__ de,
    unsigned short* __restrict__ hidbf, unsigned short* __restrict__ wbf,
    unsigned short* __restrict__ ebf) {
  int g = blockIdx.x * 256 + threadIdx.x;
  if (g < HIDQ) {
    float4 s = ((const float4*)hid)[g];
    ushort4 o; o.x = f2bf(s.x); o.y = f2bf(s.y); o.z = f2bf(s.z); o.w = f2bf(s.w);
    ((ushort4*)hidbf)[g] = o;
  } else if (g < HIDQ + 3 * WQ4) {
    int r = g - HIDQ;
    int sel = r / WQ4, r2 = r - sel * WQ4;
    const float* src = sel == 0 ? wq : (sel == 1 ? wk : wv);
    float4 s = ((const float4*)src)[r2];
    ushort4 o; o.x = f2bf(s.x); o.y = f2bf(s.y); o.z = f2bf(s.z); o.w = f2bf(s.w);
    ((ushort4*)wbf)[r] = o;
  } else {
    int r = g - HIDQ - 3 * WQ4;      // [0, 32768)
    int e = 4 * r;                   // element index into 2048*64
    ushort4 o;
    o.x = (e + 0 < 131008) ? f2bf(de[e + 0]) : 0;
    o.y = (e + 1 < 131008) ? f2bf(de[e + 1]) : 0;
    o.z = (e + 2 < 131008) ? f2bf(de[e + 2]) : 0;
    o.w = (e + 3 < 131008) ? f2bf(de[e + 3]) : 0;
    ((ushort4*)ebf)[r] = o;
  }
}

// ---------------------------------------------------------------------------
// Kernel 1: QKV projection GEMM.  C[m, o] = sum_i hid[m,i] * W[o,i] + bias[o]
// M=4096, N=2304 (q|k|v), K=768. 128x128 tile, BK=64, 4 waves (64x64 each).
// Outputs: q,k -> [bh][s][64] bf16 ; v -> transposed [bh][d][1024] bf16.
// ---------------------------------------------------------------------------
__global__ __launch_bounds__(256, 2) void qkv_gemm(
    const unsigned short* __restrict__ hidbf,   // [4096][768]
    const unsigned short* __restrict__ wbf,     // [3][768][768]
    const float* __restrict__ bq, const float* __restrict__ bk,
    const float* __restrict__ bv,
    unsigned short* __restrict__ qb, unsigned short* __restrict__ kb,
    unsigned short* __restrict__ vtb) {
  __shared__ unsigned short lda[128 * 64];   // 16KB, xor-swizzled 16B chunks
  __shared__ unsigned short ldb[128 * 64];   // 16KB
  const int tid = threadIdx.x;
  const int w = tid >> 6, lane = tid & 63, quad = lane >> 4, l15 = lane & 15;
  const int m0 = blockIdx.x * 128;
  const int bn = blockIdx.y;
  const int sel = bn / 6;
  const int nc0 = (bn - sel * 6) * 128;
  const unsigned short* wsrc = wbf + (size_t)sel * 589824;

  f32x4 acc[4][4];
#pragma unroll
  for (int i = 0; i < 4; ++i)
#pragma unroll
    for (int j = 0; j < 4; ++j) acc[i][j] = (f32x4){0.f, 0.f, 0.f, 0.f};

  const int rA = 64 * (w & 1);
  const int rB = 64 * (w >> 1);

  for (int kit = 0; kit < 12; ++kit) {
    int k0 = kit * 64;
    __syncthreads();
    // stage A,B: [128 rows][64 bf16]; chunk-linear = row*8 + cpos, xor swizzle
#pragma unroll
    for (int i = 0; i < 4; ++i) {
      int cl = (w * 4 + i) * 64 + lane;
      int row = cl >> 3, cp = cl & 7, gch = cp ^ (row & 7);
      __builtin_amdgcn_global_load_lds(
          (GCV*)(hidbf + (size_t)(m0 + row) * 768 + k0 + gch * 8),
          (LDSV*)(lda + (size_t)(w * 4 + i) * 512), 16, 0, 0);
      __builtin_amdgcn_global_load_lds(
          (GCV*)(wsrc + (size_t)(nc0 + row) * 768 + k0 + gch * 8),
          (LDSV*)(ldb + (size_t)(w * 4 + i) * 512), 16, 0, 0);
    }
    __syncthreads();

    s16x8 af[4][2], bfr[4][2];
#pragma unroll
    for (int mt = 0; mt < 4; ++mt)
#pragma unroll
      for (int ks = 0; ks < 2; ++ks) {
        int row = rA + 16 * mt + l15;
        af[mt][ks] = *(const s16x8*)(lda + row * 64 + (((quad + 4 * ks) ^ (row & 7)) * 8));
        int rowb = rB + 16 * mt + l15;
        bfr[mt][ks] = *(const s16x8*)(ldb + rowb * 64 + (((quad + 4 * ks) ^ (rowb & 7)) * 8));
      }
#pragma unroll
    for (int mt = 0; mt < 4; ++mt)
#pragma unroll
      for (int nt = 0; nt < 4; ++nt) {
        acc[mt][nt] = MFMA(af[mt][0], bfr[nt][0], acc[mt][nt]);
        acc[mt][nt] = MFMA(af[mt][1], bfr[nt][1], acc[mt][nt]);
      }
  }

  const float* bias = sel == 0 ? bq : (sel == 1 ? bk : bv);
#pragma unroll
  for (int nt = 0; nt < 4; ++nt) {
    int oc = nc0 + rB + 16 * nt + l15;          // [0,768)
    float bvl = bias[oc];
    int h = oc >> 6, dd = oc & 63;
#pragma unroll
    for (int mt = 0; mt < 4; ++mt) {
      int mbase = m0 + rA + 16 * mt + quad * 4;
      int b = mbase >> 10, s = mbase & 1023;
      size_t bh = (size_t)(b * 12 + h);
      if (sel < 2) {
        unsigned short* dst = (sel == 0 ? qb : kb) + bh * 65536 + (size_t)s * 64 + dd;
#pragma unroll
        for (int r = 0; r < 4; ++r) dst[(size_t)r * 64] = f2bf(acc[mt][nt][r] + bvl);
      } else {
        ushort4 pk;
        pk.x = f2bf(acc[mt][nt][0] + bvl); pk.y = f2bf(acc[mt][nt][1] + bvl);
        pk.z = f2bf(acc[mt][nt][2] + bvl); pk.w = f2bf(acc[mt][nt][3] + bvl);
        *(ushort4*)(vtb + bh * 65536 + (size_t)dd * 1024 + s) = pk;
      }
    }
  }
}

// ---------------------------------------------------------------------------
// Kernel 2: fused attention. One block = (bh, 64 q-rows). 4 waves, wave w owns
// i-strip [16w,16w+16). S computed TRANSPOSED (A=k,B=q): lane holds
// St[j=16mt+4q+r][i=l15]. Bias via Qe=q@E^T (per-wave) and Ke=k@E^T (coop),
// sheared through LDS at READ time (v1-verified gather). Max-free online
// softmax (per-lane row sums). PV uses P re-laid through LDS as A-frag;
// V pre-transposed for contiguous B-frag. E read direct from global (L2),
// batched 3+2 to bound register pressure.
// ---------------------------------------------------------------------------
__global__ __launch_bounds__(256, 2) void attn_kernel(
    const unsigned short* __restrict__ qb, const unsigned short* __restrict__ kb,
    const unsigned short* __restrict__ vtb, const unsigned short* __restrict__ ebf,
    const float* __restrict__ mask, float* __restrict__ out) {
  __shared__ unsigned short ksw[64 * 64];        // 8KB  swizzled
  __shared__ unsigned short vsw[64 * 64];        // 8KB  swizzled (rows = d)
  __shared__ unsigned short keb[128 * 70];       // 17.5KB Ke[t][j] bf16, stride 70
  __shared__ unsigned short qeb[4][16 * 88];     // 11KB per-wave Qe[i][t'] / P[i][j]
  __shared__ float ml[1024];                     // 4KB  mask row * log2(e)

  const int tid = threadIdx.x;
  const int w = tid >> 6, lane = tid & 63, quad = lane >> 4, l15 = lane & 15;
  const int blk0 = blockIdx.x;
  const int blk = (blk0 & 7) * 96 + (blk0 >> 3);   // XCD-bijective (768 = 8*96):
  const int bh = blk >> 4;                         // all 16 l-tiles of a bh on one XCD
  const int l0 = (blk & 15) << 6;
  const int b = bh / 12;
  const int h = bh - b * 12;

  const float SC1 = 0.18033688f;   // log2(e)/8
  const float SC2 = 1.44269504f;   // log2(e)

  // stage mask row (pre-scaled); ordered before first use by loop barriers
  {
    float4 mv = ((const float4*)(mask + (size_t)b * 1024))[tid];
    float4 ms; ms.x = mv.x * SC2; ms.y = mv.y * SC2; ms.z = mv.z * SC2; ms.w = mv.w * SC2;
    ((float4*)ml)[tid] = ms;
  }

  // q B-frags for strip row l0+16w+l15 (held all 16 iters)
  const unsigned short* qrow = qb + (size_t)bh * 65536 + (size_t)(l0 + 16 * w + l15) * 64;
  s16x8 qf[2];
  qf[0] = *(const s16x8*)(qrow + quad * 8);
  qf[1] = *(const s16x8*)(qrow + 32 + quad * 8);

  f32x4 oacc[4];
#pragma unroll
  for (int i = 0; i < 4; ++i) oacc[i] = (f32x4){0.f, 0.f, 0.f, 0.f};
  float lsum = 0.f;

  const unsigned short* kbh = kb + (size_t)bh * 65536;
  const unsigned short* vbh = vtb + (size_t)bh * 65536;

  for (int it = 0; it < 16; ++it) {
    const int r0 = it << 6;
    const int dbase = l0 - r0 + 960;   // E row for t=0 (t = i - j + 63, block-local)
    __syncthreads();
    // ---- stage k (2 issues/wave), vt (2) via global_load_lds x16B
    {
      const unsigned short* kbase = kbh + (size_t)r0 * 64;
#pragma unroll
      for (int i = 0; i < 2; ++i) {
        int cl = (w * 2 + i) * 64 + lane;
        int row = cl >> 3, cp = cl & 7, gch = cp ^ (row & 7);
        __builtin_amdgcn_global_load_lds((GCV*)(kbase + row * 64 + gch * 8),
                                         (LDSV*)(ksw + (size_t)(w * 2 + i) * 512), 16, 0, 0);
      }
      const unsigned short* vbase = vbh + r0;
#pragma unroll
      for (int i = 0; i < 2; ++i) {
        int cl = (w * 2 + i) * 64 + lane;
        int row = cl >> 3, cp = cl & 7, gch = cp ^ (row & 7);
        __builtin_amdgcn_global_load_lds((GCV*)(vbase + (size_t)row * 1024 + gch * 8),
                                         (LDSV*)(vsw + (size_t)(w * 2 + i) * 512), 16, 0, 0);
      }
    }
    __syncthreads();

    // ---- E loads (direct from global, L2-resident) + tile processing.
    auto load_e = [&](int tt, s16x8* dst) {
      const unsigned short* erow =
          ebf + (((size_t)(dbase + 16 * tt + l15)) << 6) + quad * 8;
      dst[0] = *(const s16x8*)(erow);
      dst[1] = *(const s16x8*)(erow + 32);
    };

    // batch1: tiles w+0, w+1, w+2 (latency hides under kf ds_reads + St MFMA)
    s16x8 efA0[2], efA1[2], efA2[2];
    load_e(w + 0, efA0);
    load_e(w + 1, efA1);
    load_e(w + 2, efA2);

    // ---- k A-frags (feed St and Ke)
    s16x8 kf[4][2];
#pragma unroll
    for (int mt = 0; mt < 4; ++mt)
#pragma unroll
      for (int ks = 0; ks < 2; ++ks) {
        int row = 16 * mt + l15;
        kf[mt][ks] = *(const s16x8*)(ksw + row * 64 + (((quad + 4 * ks) ^ (row & 7)) * 8));
      }

    // ---- St[j][i] = k . q
    f32x4 st[4];
#pragma unroll
    for (int mt = 0; mt < 4; ++mt) {
      f32x4 a = (f32x4){0.f, 0.f, 0.f, 0.f};
      a = MFMA(kf[mt][0], qf[0], a);
      a = MFMA(kf[mt][1], qf[1], a);
      st[mt] = a;
    }

    // ---- per-tile: Qe compute + immediate LDS store; Ke piggyback on the
    // two tiles this wave owns (tt = 2w, 2w+1 via tp==w, tp==w+1).
    auto do_tile = [&](int tp, const s16x8& e0, const s16x8& e1) {
      f32x4 a = (f32x4){0.f, 0.f, 0.f, 0.f};
      a = MFMA(qf[0], e0, a);
      a = MFMA(qf[1], e1, a);
      unsigned short* base = &qeb[w][0];
#pragma unroll
      for (int r = 0; r < 4; ++r)
        base[(quad * 4 + r) * 88 + 16 * tp + l15] = f2bf(a[r]);
      if (tp == w || tp == w + 1) {
        int tt = w + tp;
#pragma unroll
        for (int mt = 0; mt < 4; ++mt) {
          f32x4 ka = (f32x4){0.f, 0.f, 0.f, 0.f};
          ka = MFMA(kf[mt][0], e0, ka);
          ka = MFMA(kf[mt][1], e1, ka);
          int t = 16 * tt + l15;
          int jb = 16 * mt + 4 * quad;
          unsigned short* p = keb + t * 70 + jb;
          uint32_t p0 = (uint32_t)f2bf(ka[0]) | ((uint32_t)f2bf(ka[1]) << 16);
          uint32_t p1 = (uint32_t)f2bf(ka[2]) | ((uint32_t)f2bf(ka[3]) << 16);
          *(uint32_t*)(p) = p0;
          *(uint32_t*)(p + 2) = p1;
        }
      }
    };

    do_tile(0, efA0[0], efA0[1]);
    // batch2 issued here: latency hides under tiles 1-2 processing
    s16x8 efB3[2], efB4[2];
    load_e(w + 3, efB3);
    load_e(w + 4, efB4);
    do_tile(1, efA1[0], efA1[1]);
    do_tile(2, efA2[0], efA2[1]);
    do_tile(3, efB3[0], efB3[1]);
    do_tile(4, efB4[0], efB4[1]);

    __syncthreads();   // keb (cross-wave) + qeb ready

    // ---- gather shear + max-free softmax; lane's i = l15 (strip-local)
    float pr[4][4];
    const float* mlr = ml + r0;
#pragma unroll
    for (int mt = 0; mt < 4; ++mt)
#pragma unroll
      for (int r = 0; r < 4; ++r) {
        int j = 16 * mt + 4 * quad + r;
        int tp_ = l15 - j + 63;          // [0,78]
        float qv = bf2f(qeb[w][l15 * 88 + tp_]);
        float kv = bf2f(keb[(16 * w + tp_) * 70 + j]);
        float p = exp2f((st[mt][r] + qv + kv) * SC1 + mlr[j]);
        pr[mt][r] = p;
        lsum += p;
      }

    // ---- P -> LDS as [i=l15][j] (reuse qeb region), then A-frags
    {
      unsigned short* base = &qeb[w][0];
#pragma unroll
      for (int mt = 0; mt < 4; ++mt)
#pragma unroll
        for (int r = 0; r < 4; ++r) {
          int j = 16 * mt + 4 * quad + r;
          base[l15 * 88 + j] = f2bf(pr[mt][r]);
        }
    }
    s16x8 pf0 = *(const s16x8*)(&qeb[w][0] + l15 * 88 + quad * 8);
    s16x8 pf1 = *(const s16x8*)(&qeb[w][0] + l15 * 88 + 32 + quad * 8);

    // ---- O += P @ V  (B-frags from transposed V in LDS)
#pragma unroll
    for (int dt = 0; dt < 4; ++dt) {
      int row = 16 * dt + l15;
      s16x8 vf0 = *(const s16x8*)(vsw + row * 64 + ((quad ^ (row & 7)) * 8));
      s16x8 vf1 = *(const s16x8*)(vsw + row * 64 + (((quad + 4) ^ (row & 7)) * 8));
      oacc[dt] = MFMA(pf0, vf0, oacc[dt]);
      oacc[dt] = MFMA(pf1, vf1, oacc[dt]);
    }
  }

  // ---- finalize: row sums live per-lane (i=l15); combine quads, divide, store
  lsum += __shfl_xor(lsum, 16, 64);
  lsum += __shfl_xor(lsum, 32, 64);
#pragma unroll
  for (int r = 0; r < 4; ++r) {
    float ls = __shfl(lsum, quad * 4 + r, 64);
    float rinv = 1.0f / ls;
    int l = l0 + 16 * w + quad * 4 + r;
    float* dst = out + ((size_t)(b * 1024 + l)) * 768 + h * 64;
#pragma unroll
    for (int dt = 0; dt < 4; ++dt) dst[16 * dt + l15] = oacc[dt][r] * rinv;
  }
}

// ---------------------------------------------------------------------------
extern "C" void kernel_launch(void* const* d_in, const int* in_sizes, int n_in,
                              void* d_out, int out_size, void* d_ws, size_t ws_size,
                              hipStream_t stream) {
  const float* hid  = (const float*)d_in[0];
  const float* mask = (const float*)d_in[1];
  const float* wq   = (const float*)d_in[2];
  const float* bq   = (const float*)d_in[3];
  const float* wk   = (const float*)d_in[4];
  const float* bk   = (const float*)d_in[5];
  const float* wv   = (const float*)d_in[6];
  const float* bv   = (const float*)d_in[7];
  const float* de   = (const float*)d_in[8];

  char* ws = (char*)d_ws;
  unsigned short* hidbf = (unsigned short*)(ws);                  // 6,291,456 B
  unsigned short* wbf   = (unsigned short*)(ws + 6291456);        // 3,538,944 B
  unsigned short* ebf   = (unsigned short*)(ws + 9830400);        //   262,144 B
  unsigned short* qb    = (unsigned short*)(ws + 10092544);       // 6,291,456 B
  unsigned short* kb    = (unsigned short*)(ws + 16384000);       // 6,291,456 B
  unsigned short* vtb   = (unsigned short*)(ws + 22675456);       // 6,291,456 B

  convert_kernel<<<4928, 256, 0, stream>>>(hid, wq, wk, wv, de, hidbf, wbf, ebf);
  qkv_gemm<<<dim3(32, 18), 256, 0, stream>>>(hidbf, wbf, bq, bk, bv, qb, kb, vtb);
  attn_kernel<<<768, 256, 0, stream>>>(qb, kb, vtb, ebf, mask, (float*)d_out);
}

// Round 4
// 192.452 us; speedup vs baseline: 1.1617x; 1.1617x over previous
//
#include <hip/hip_runtime.h>
#include <stdint.h>

// ---------------------------------------------------------------------------
// BertSelfAttention (relative_key_query) on gfx950.
// B=4 S=1024 H=768 nH=12 dH=64 MAXPOS=1024.
//   q,k,v = hidden @ W{q,k,v}.T + b        (bf16 MFMA GEMM)
//   S[l,r] = q.k + q.E[l-r+1023] + k.E[l-r+1023];  softmax(S/8 + mask) @ v
// Pipeline: convert(fp32->bf16) -> qkv_gemm -> fused flash attention.
// v5 attn = v1 structure (esw async-staged: E-in-VGPR refuted both ways —
// spills at big reg budget (R2), serializes at small (R3)) plus:
//   - ml mask in LDS, float4 reads (broadcast, conflict-free).
//   - XCD-bijective swizzle (FETCH 53.7 -> ~17MB verified).
//   - keb stride 68 (70 RAISED conflicts 2.75->4.33M; empirical revert).
//   - LDS write vectorization: Qe stored transposed [t'][i] => 5 ds_write_b64
//     (was 20 scalar); P pairs => 4 b64 (was 16 scalar); keb => 4 b64.
// LDS 74.5KB, 2 blocks/CU.
// ---------------------------------------------------------------------------

typedef __attribute__((ext_vector_type(4))) float f32x4;
typedef __attribute__((ext_vector_type(8))) short s16x8;
typedef const __attribute__((address_space(1))) void GCV;
typedef __attribute__((address_space(3))) void LDSV;

__device__ __forceinline__ unsigned short f2bf(float f) {
  union { float f; uint32_t u; } v; v.f = f;
  uint32_t r = (v.u + 0x7FFFu + ((v.u >> 16) & 1u)) >> 16;
  return (unsigned short)r;
}
__device__ __forceinline__ float bf2f(unsigned short b) {
  union { uint32_t u; float f; } v; v.u = ((uint32_t)b) << 16;
  return v.f;
}
__device__ __forceinline__ uint32_t packbf(float a, float b) {
  return (uint32_t)f2bf(a) | ((uint32_t)f2bf(b) << 16);
}

#define MFMA(a, b, c) __builtin_amdgcn_mfma_f32_16x16x32_bf16((a), (b), (c), 0, 0, 0)

// ---------------------------------------------------------------------------
// Kernel 0: fp32 -> bf16 conversion. hidden [4096x768], Wq|Wk|Wv [768x768]x3,
// dist_emb [2047x64] padded to 2048 rows (row 2047 = 0).
// ---------------------------------------------------------------------------
#define HIDQ 786432   // 4096*768/4
#define WQ4  147456   // 768*768/4
#define EQ4  32768    // 2048*64/4

__global__ __launch_bounds__(256) void convert_kernel(
    const float* __restrict__ hid, const float* __restrict__ wq,
    const float* __restrict__ wk, const float* __restrict__ wv,
    const float* __restrict__ de,
    unsigned short* __restrict__ hidbf, unsigned short* __restrict__ wbf,
    unsigned short* __restrict__ ebf) {
  int g = blockIdx.x * 256 + threadIdx.x;
  if (g < HIDQ) {
    float4 s = ((const float4*)hid)[g];
    ushort4 o; o.x = f2bf(s.x); o.y = f2bf(s.y); o.z = f2bf(s.z); o.w = f2bf(s.w);
    ((ushort4*)hidbf)[g] = o;
  } else if (g < HIDQ + 3 * WQ4) {
    int r = g - HIDQ;
    int sel = r / WQ4, r2 = r - sel * WQ4;
    const float* src = sel == 0 ? wq : (sel == 1 ? wk : wv);
    float4 s = ((const float4*)src)[r2];
    ushort4 o; o.x = f2bf(s.x); o.y = f2bf(s.y); o.z = f2bf(s.z); o.w = f2bf(s.w);
    ((ushort4*)wbf)[r] = o;
  } else {
    int r = g - HIDQ - 3 * WQ4;      // [0, 32768)
    int e = 4 * r;                   // element index into 2048*64
    ushort4 o;
    o.x = (e + 0 < 131008) ? f2bf(de[e + 0]) : 0;
    o.y = (e + 1 < 131008) ? f2bf(de[e + 1]) : 0;
    o.z = (e + 2 < 131008) ? f2bf(de[e + 2]) : 0;
    o.w = (e + 3 < 131008) ? f2bf(de[e + 3]) : 0;
    ((ushort4*)ebf)[r] = o;
  }
}

// ---------------------------------------------------------------------------
// Kernel 1: QKV projection GEMM.  C[m, o] = sum_i hid[m,i] * W[o,i] + bias[o]
// M=4096, N=2304 (q|k|v), K=768. 128x128 tile, BK=64, 4 waves (64x64 each).
// Outputs: q,k -> [bh][s][64] bf16 ; v -> transposed [bh][d][1024] bf16.
// ---------------------------------------------------------------------------
__global__ __launch_bounds__(256, 2) void qkv_gemm(
    const unsigned short* __restrict__ hidbf,   // [4096][768]
    const unsigned short* __restrict__ wbf,     // [3][768][768]
    const float* __restrict__ bq, const float* __restrict__ bk,
    const float* __restrict__ bv,
    unsigned short* __restrict__ qb, unsigned short* __restrict__ kb,
    unsigned short* __restrict__ vtb) {
  __shared__ unsigned short lda[128 * 64];   // 16KB, xor-swizzled 16B chunks
  __shared__ unsigned short ldb[128 * 64];   // 16KB
  const int tid = threadIdx.x;
  const int w = tid >> 6, lane = tid & 63, quad = lane >> 4, l15 = lane & 15;
  const int m0 = blockIdx.x * 128;
  const int bn = blockIdx.y;
  const int sel = bn / 6;
  const int nc0 = (bn - sel * 6) * 128;
  const unsigned short* wsrc = wbf + (size_t)sel * 589824;

  f32x4 acc[4][4];
#pragma unroll
  for (int i = 0; i < 4; ++i)
#pragma unroll
    for (int j = 0; j < 4; ++j) acc[i][j] = (f32x4){0.f, 0.f, 0.f, 0.f};

  const int rA = 64 * (w & 1);
  const int rB = 64 * (w >> 1);

  for (int kit = 0; kit < 12; ++kit) {
    int k0 = kit * 64;
    __syncthreads();
    // stage A,B: [128 rows][64 bf16]; chunk-linear = row*8 + cpos, xor swizzle
#pragma unroll
    for (int i = 0; i < 4; ++i) {
      int cl = (w * 4 + i) * 64 + lane;
      int row = cl >> 3, cp = cl & 7, gch = cp ^ (row & 7);
      __builtin_amdgcn_global_load_lds(
          (GCV*)(hidbf + (size_t)(m0 + row) * 768 + k0 + gch * 8),
          (LDSV*)(lda + (size_t)(w * 4 + i) * 512), 16, 0, 0);
      __builtin_amdgcn_global_load_lds(
          (GCV*)(wsrc + (size_t)(nc0 + row) * 768 + k0 + gch * 8),
          (LDSV*)(ldb + (size_t)(w * 4 + i) * 512), 16, 0, 0);
    }
    __syncthreads();

    s16x8 af[4][2], bfr[4][2];
#pragma unroll
    for (int mt = 0; mt < 4; ++mt)
#pragma unroll
      for (int ks = 0; ks < 2; ++ks) {
        int row = rA + 16 * mt + l15;
        af[mt][ks] = *(const s16x8*)(lda + row * 64 + (((quad + 4 * ks) ^ (row & 7)) * 8));
        int rowb = rB + 16 * mt + l15;
        bfr[mt][ks] = *(const s16x8*)(ldb + rowb * 64 + (((quad + 4 * ks) ^ (rowb & 7)) * 8));
      }
#pragma unroll
    for (int mt = 0; mt < 4; ++mt)
#pragma unroll
      for (int nt = 0; nt < 4; ++nt) {
        acc[mt][nt] = MFMA(af[mt][0], bfr[nt][0], acc[mt][nt]);
        acc[mt][nt] = MFMA(af[mt][1], bfr[nt][1], acc[mt][nt]);
      }
  }

  const float* bias = sel == 0 ? bq : (sel == 1 ? bk : bv);
#pragma unroll
  for (int nt = 0; nt < 4; ++nt) {
    int oc = nc0 + rB + 16 * nt + l15;          // [0,768)
    float bvl = bias[oc];
    int h = oc >> 6, dd = oc & 63;
#pragma unroll
    for (int mt = 0; mt < 4; ++mt) {
      int mbase = m0 + rA + 16 * mt + quad * 4;
      int b = mbase >> 10, s = mbase & 1023;
      size_t bh = (size_t)(b * 12 + h);
      if (sel < 2) {
        unsigned short* dst = (sel == 0 ? qb : kb) + bh * 65536 + (size_t)s * 64 + dd;
#pragma unroll
        for (int r = 0; r < 4; ++r) dst[(size_t)r * 64] = f2bf(acc[mt][nt][r] + bvl);
      } else {
        ushort4 pk;
        pk.x = f2bf(acc[mt][nt][0] + bvl); pk.y = f2bf(acc[mt][nt][1] + bvl);
        pk.z = f2bf(acc[mt][nt][2] + bvl); pk.w = f2bf(acc[mt][nt][3] + bvl);
        *(ushort4*)(vtb + bh * 65536 + (size_t)dd * 1024 + s) = pk;
      }
    }
  }
}

// ---------------------------------------------------------------------------
// Kernel 2: fused attention. One block = (bh, 64 q-rows). 4 waves, wave w owns
// i-strip [16w,16w+16). S computed TRANSPOSED (A=k,B=q): lane holds
// St[j=16mt+4q+r][i=l15]. Bias via Qe=q@E^T (per-wave) and Ke=k@E^T (coop),
// sheared through LDS at READ time. Max-free online softmax. PV via P through
// LDS as A-frag; V pre-transposed. E async-staged to esw (global_load_lds).
// ---------------------------------------------------------------------------
__global__ __launch_bounds__(256, 2) void attn_kernel(
    const unsigned short* __restrict__ qb, const unsigned short* __restrict__ kb,
    const unsigned short* __restrict__ vtb, const unsigned short* __restrict__ ebf,
    const float* __restrict__ mask, float* __restrict__ out) {
  __shared__ unsigned short ksw[64 * 64];        // 8KB  swizzled
  __shared__ unsigned short vsw[64 * 64];        // 8KB  swizzled (rows = d)
  __shared__ unsigned short esw[128 * 64];       // 16KB swizzled (rows = t)
  __shared__ unsigned short keb[128 * 68];       // 17KB Ke[t][j] bf16, stride 68
  __shared__ unsigned short qet[4][80 * 20];     // 12.5KB per-wave Qe^T [t'][i]
  __shared__ unsigned short pwl[4][16 * 72];     // 9KB  per-wave P[i][j]
  __shared__ float ml[1024];                     // 4KB  mask row * log2(e)

  const int tid = threadIdx.x;
  const int w = tid >> 6, lane = tid & 63, quad = lane >> 4, l15 = lane & 15;
  const int blk0 = blockIdx.x;
  const int blk = (blk0 & 7) * 96 + (blk0 >> 3);   // XCD-bijective (768 = 8*96):
  const int bh = blk >> 4;                         // all 16 l-tiles of a bh on one XCD
  const int l0 = (blk & 15) << 6;
  const int b = bh / 12;
  const int h = bh - b * 12;

  const float SC1 = 0.18033688f;   // log2(e)/8
  const float SC2 = 1.44269504f;   // log2(e)

  // stage mask row (pre-scaled); ordered before first use by loop barriers
  {
    float4 mv = ((const float4*)(mask + (size_t)b * 1024))[tid];
    float4 ms; ms.x = mv.x * SC2; ms.y = mv.y * SC2; ms.z = mv.z * SC2; ms.w = mv.w * SC2;
    ((float4*)ml)[tid] = ms;
  }

  // q B-frags for strip row l0+16w+l15 (held all 16 iters)
  const unsigned short* qrow = qb + (size_t)bh * 65536 + (size_t)(l0 + 16 * w + l15) * 64;
  s16x8 qf[2];
  qf[0] = *(const s16x8*)(qrow + quad * 8);
  qf[1] = *(const s16x8*)(qrow + 32 + quad * 8);

  f32x4 oacc[4];
#pragma unroll
  for (int i = 0; i < 4; ++i) oacc[i] = (f32x4){0.f, 0.f, 0.f, 0.f};
  float lsum = 0.f;

  const unsigned short* kbh = kb + (size_t)bh * 65536;
  const unsigned short* vbh = vtb + (size_t)bh * 65536;
  unsigned short* qtw = &qet[w][0];
  unsigned short* pww = &pwl[w][0];

  for (int it = 0; it < 16; ++it) {
    const int r0 = it << 6;
    const int dbase = l0 - r0 + 960;   // E row for t=0 (t = i - j + 63, block-local)
    __syncthreads();
    // ---- stage k (2 issues/wave), vt (2), E (4) via global_load_lds x16B
    {
      const unsigned short* kbase = kbh + (size_t)r0 * 64;
#pragma unroll
      for (int i = 0; i < 2; ++i) {
        int cl = (w * 2 + i) * 64 + lane;
        int row = cl >> 3, cp = cl & 7, gch = cp ^ (row & 7);
        __builtin_amdgcn_global_load_lds((GCV*)(kbase + row * 64 + gch * 8),
                                         (LDSV*)(ksw + (size_t)(w * 2 + i) * 512), 16, 0, 0);
      }
      const unsigned short* vbase = vbh + r0;
#pragma unroll
      for (int i = 0; i < 2; ++i) {
        int cl = (w * 2 + i) * 64 + lane;
        int row = cl >> 3, cp = cl & 7, gch = cp ^ (row & 7);
        __builtin_amdgcn_global_load_lds((GCV*)(vbase + (size_t)row * 1024 + gch * 8),
                                         (LDSV*)(vsw + (size_t)(w * 2 + i) * 512), 16, 0, 0);
      }
      const unsigned short* ebase = ebf + (size_t)dbase * 64;
#pragma unroll
      for (int i = 0; i < 4; ++i) {
        int cl = (w * 4 + i) * 64 + lane;
        int row = cl >> 3, cp = cl & 7, gch = cp ^ (row & 7);
        __builtin_amdgcn_global_load_lds((GCV*)(ebase + row * 64 + gch * 8),
                                         (LDSV*)(esw + (size_t)(w * 4 + i) * 512), 16, 0, 0);
      }
    }
    __syncthreads();

    // ---- k A-frags (feed St and Ke)
    s16x8 kf[4][2];
#pragma unroll
    for (int mt = 0; mt < 4; ++mt)
#pragma unroll
      for (int ks = 0; ks < 2; ++ks) {
        int row = 16 * mt + l15;
        kf[mt][ks] = *(const s16x8*)(ksw + row * 64 + (((quad + 4 * ks) ^ (row & 7)) * 8));
      }

    // ---- St[j][i] = k . q
    f32x4 st[4];
#pragma unroll
    for (int mt = 0; mt < 4; ++mt) {
      f32x4 a = (f32x4){0.f, 0.f, 0.f, 0.f};
      a = MFMA(kf[mt][0], qf[0], a);
      a = MFMA(kf[mt][1], qf[1], a);
      st[mt] = a;
    }

    // ---- Qe (wave window t-tiles [w, w+4]) -> qet[t'=16tp+l15][i=4quad+r]
    // (one b64 write per tile). Ke piggybacks on tp==w, w+1 (wave-uniform).
#pragma unroll
    for (int tp = 0; tp < 5; ++tp) {
      int tt = w + tp;
      int row = 16 * tt + l15;
      s16x8 ef0 = *(const s16x8*)(esw + row * 64 + ((quad ^ (row & 7)) * 8));
      s16x8 ef1 = *(const s16x8*)(esw + row * 64 + (((quad + 4) ^ (row & 7)) * 8));
      f32x4 a = (f32x4){0.f, 0.f, 0.f, 0.f};
      a = MFMA(qf[0], ef0, a);
      a = MFMA(qf[1], ef1, a);
      {
        uint2 pk; pk.x = packbf(a[0], a[1]); pk.y = packbf(a[2], a[3]);
        *(uint2*)(qtw + (16 * tp + l15) * 20 + 4 * quad) = pk;
      }
      if (tp == w || tp == w + 1) {   // this wave owns Ke tiles 2w, 2w+1
#pragma unroll
        for (int mt = 0; mt < 4; ++mt) {
          f32x4 ka = (f32x4){0.f, 0.f, 0.f, 0.f};
          ka = MFMA(kf[mt][0], ef0, ka);
          ka = MFMA(kf[mt][1], ef1, ka);
          int t = 16 * tt + l15;
          int jb = 16 * mt + 4 * quad;
          uint2 pk; pk.x = packbf(ka[0], ka[1]); pk.y = packbf(ka[2], ka[3]);
          *(uint2*)(keb + t * 68 + jb) = pk;
        }
      }
    }
    __syncthreads();   // keb (cross-wave) + qet ready

    // ---- gather shear + max-free softmax; lane's i = l15 (strip-local)
    float pr[4][4];
    const float* mlr = ml + r0;
#pragma unroll
    for (int mt = 0; mt < 4; ++mt) {
      int jb = 16 * mt + 4 * quad;
      float4 mk4 = *(const float4*)(mlr + jb);
#pragma unroll
      for (int r = 0; r < 4; ++r) {
        int j = jb + r;
        int tp_ = l15 - j + 63;          // [0,78]
        float qv = bf2f(qtw[tp_ * 20 + l15]);
        float kv = bf2f(keb[(16 * w + tp_) * 68 + j]);
        float p = exp2f((st[mt][r] + qv + kv) * SC1 + ((const float*)&mk4)[r]);
        pr[mt][r] = p;
        lsum += p;
      }
    }

    // ---- P -> per-wave LDS [i=l15][j], b64 stores; then A-frags
#pragma unroll
    for (int mt = 0; mt < 4; ++mt) {
      uint2 pk; pk.x = packbf(pr[mt][0], pr[mt][1]); pk.y = packbf(pr[mt][2], pr[mt][3]);
      *(uint2*)(pww + l15 * 72 + 16 * mt + 4 * quad) = pk;
    }
    s16x8 pf0 = *(const s16x8*)(pww + l15 * 72 + quad * 8);
    s16x8 pf1 = *(const s16x8*)(pww + l15 * 72 + 32 + quad * 8);

    // ---- O += P @ V  (B-frags from transposed V in LDS)
#pragma unroll
    for (int dt = 0; dt < 4; ++dt) {
      int row = 16 * dt + l15;
      s16x8 vf0 = *(const s16x8*)(vsw + row * 64 + ((quad ^ (row & 7)) * 8));
      s16x8 vf1 = *(const s16x8*)(vsw + row * 64 + (((quad + 4) ^ (row & 7)) * 8));
      oacc[dt] = MFMA(pf0, vf0, oacc[dt]);
      oacc[dt] = MFMA(pf1, vf1, oacc[dt]);
    }
  }

  // ---- finalize: row sums live per-lane (i=l15); combine quads, divide, store
  lsum += __shfl_xor(lsum, 16, 64);
  lsum += __shfl_xor(lsum, 32, 64);
#pragma unroll
  for (int r = 0; r < 4; ++r) {
    float ls = __shfl(lsum, quad * 4 + r, 64);
    float rinv = 1.0f / ls;
    int l = l0 + 16 * w + quad * 4 + r;
    float* dst = out + ((size_t)(b * 1024 + l)) * 768 + h * 64;
#pragma unroll
    for (int dt = 0; dt < 4; ++dt) dst[16 * dt + l15] = oacc[dt][r] * rinv;
  }
}

// ---------------------------------------------------------------------------
extern "C" void kernel_launch(void* const* d_in, const int* in_sizes, int n_in,
                              void* d_out, int out_size, void* d_ws, size_t ws_size,
                              hipStream_t stream) {
  const float* hid  = (const float*)d_in[0];
  const float* mask = (const float*)d_in[1];
  const float* wq   = (const float*)d_in[2];
  const float* bq   = (const float*)d_in[3];
  const float* wk   = (const float*)d_in[4];
  const float* bk   = (const float*)d_in[5];
  const float* wv   = (const float*)d_in[6];
  const float* bv   = (const float*)d_in[7];
  const float* de   = (const float*)d_in[8];

  char* ws = (char*)d_ws;
  unsigned short* hidbf = (unsigned short*)(ws);                  // 6,291,456 B
  unsigned short* wbf   = (unsigned short*)(ws + 6291456);        // 3,538,944 B
  unsigned short* ebf   = (unsigned short*)(ws + 9830400);        //   262,144 B
  unsigned short* qb    = (unsigned short*)(ws + 10092544);       // 6,291,456 B
  unsigned short* kb    = (unsigned short*)(ws + 16384000);       // 6,291,456 B
  unsigned short* vtb   = (unsigned short*)(ws + 22675456);       // 6,291,456 B

  convert_kernel<<<4928, 256, 0, stream>>>(hid, wq, wk, wv, de, hidbf, wbf, ebf);
  qkv_gemm<<<dim3(32, 18), 256, 0, stream>>>(hidbf, wbf, bq, bk, bv, qb, kb, vtb);
  attn_kernel<<<768, 256, 0, stream>>>(qb, kb, vtb, ebf, mask, (float*)d_out);
}

// Round 5
// 184.446 us; speedup vs baseline: 1.2121x; 1.0434x over previous
//
#include <hip/hip_runtime.h>
#include <stdint.h>

// ---------------------------------------------------------------------------
// BertSelfAttention (relative_key_query) on gfx950.
// B=4 S=1024 H=768 nH=12 dH=64 MAXPOS=1024.
//   q,k,v = hidden @ W{q,k,v}.T + b        (bf16 MFMA GEMM)
//   S[l,r] = q.k + q.E[l-r+1023] + k.E[l-r+1023];  softmax(S/8 + mask) @ v
// Pipeline: convert(fp32->bf16) -> qkv_gemm -> fused flash attention.
// v6 attn = v5 + staging software-pipeline:
//   - stage for it+1 issued mid-iter (after phase1 barrier), drained by the
//     top-of-loop barrier after phase2 covers the latency. 3 -> 2 barriers.
//   - vsw double-buffered (phase2 reads it while next tile lands in the
//     other slot). pwl merged into per-wave qet region (aliased, wave-
//     private, read-before-write order enforced by same-array aliasing).
//   - LDS 76.3 -> 73.5 KB, still 2 blocks/CU, no spills expected.
// ---------------------------------------------------------------------------

typedef __attribute__((ext_vector_type(4))) float f32x4;
typedef __attribute__((ext_vector_type(8))) short s16x8;
typedef const __attribute__((address_space(1))) void GCV;
typedef __attribute__((address_space(3))) void LDSV;

__device__ __forceinline__ unsigned short f2bf(float f) {
  union { float f; uint32_t u; } v; v.f = f;
  uint32_t r = (v.u + 0x7FFFu + ((v.u >> 16) & 1u)) >> 16;
  return (unsigned short)r;
}
__device__ __forceinline__ float bf2f(unsigned short b) {
  union { uint32_t u; float f; } v; v.u = ((uint32_t)b) << 16;
  return v.f;
}
__device__ __forceinline__ uint32_t packbf(float a, float b) {
  return (uint32_t)f2bf(a) | ((uint32_t)f2bf(b) << 16);
}

#define MFMA(a, b, c) __builtin_amdgcn_mfma_f32_16x16x32_bf16((a), (b), (c), 0, 0, 0)

// ---------------------------------------------------------------------------
// Kernel 0: fp32 -> bf16 conversion. hidden [4096x768], Wq|Wk|Wv [768x768]x3,
// dist_emb [2047x64] padded to 2048 rows (row 2047 = 0).
// ---------------------------------------------------------------------------
#define HIDQ 786432   // 4096*768/4
#define WQ4  147456   // 768*768/4
#define EQ4  32768    // 2048*64/4

__global__ __launch_bounds__(256) void convert_kernel(
    const float* __restrict__ hid, const float* __restrict__ wq,
    const float* __restrict__ wk, const float* __restrict__ wv,
    const float* __restrict__ de,
    unsigned short* __restrict__ hidbf, unsigned short* __restrict__ wbf,
    unsigned short* __restrict__ ebf) {
  int g = blockIdx.x * 256 + threadIdx.x;
  if (g < HIDQ) {
    float4 s = ((const float4*)hid)[g];
    ushort4 o; o.x = f2bf(s.x); o.y = f2bf(s.y); o.z = f2bf(s.z); o.w = f2bf(s.w);
    ((ushort4*)hidbf)[g] = o;
  } else if (g < HIDQ + 3 * WQ4) {
    int r = g - HIDQ;
    int sel = r / WQ4, r2 = r - sel * WQ4;
    const float* src = sel == 0 ? wq : (sel == 1 ? wk : wv);
    float4 s = ((const float4*)src)[r2];
    ushort4 o; o.x = f2bf(s.x); o.y = f2bf(s.y); o.z = f2bf(s.z); o.w = f2bf(s.w);
    ((ushort4*)wbf)[r] = o;
  } else {
    int r = g - HIDQ - 3 * WQ4;      // [0, 32768)
    int e = 4 * r;                   // element index into 2048*64
    ushort4 o;
    o.x = (e + 0 < 131008) ? f2bf(de[e + 0]) : 0;
    o.y = (e + 1 < 131008) ? f2bf(de[e + 1]) : 0;
    o.z = (e + 2 < 131008) ? f2bf(de[e + 2]) : 0;
    o.w = (e + 3 < 131008) ? f2bf(de[e + 3]) : 0;
    ((ushort4*)ebf)[r] = o;
  }
}

// ---------------------------------------------------------------------------
// Kernel 1: QKV projection GEMM.  C[m, o] = sum_i hid[m,i] * W[o,i] + bias[o]
// M=4096, N=2304 (q|k|v), K=768. 128x128 tile, BK=64, 4 waves (64x64 each).
// Outputs: q,k -> [bh][s][64] bf16 ; v -> transposed [bh][d][1024] bf16.
// ---------------------------------------------------------------------------
__global__ __launch_bounds__(256, 2) void qkv_gemm(
    const unsigned short* __restrict__ hidbf,   // [4096][768]
    const unsigned short* __restrict__ wbf,     // [3][768][768]
    const float* __restrict__ bq, const float* __restrict__ bk,
    const float* __restrict__ bv,
    unsigned short* __restrict__ qb, unsigned short* __restrict__ kb,
    unsigned short* __restrict__ vtb) {
  __shared__ unsigned short lda[128 * 64];   // 16KB, xor-swizzled 16B chunks
  __shared__ unsigned short ldb[128 * 64];   // 16KB
  const int tid = threadIdx.x;
  const int w = tid >> 6, lane = tid & 63, quad = lane >> 4, l15 = lane & 15;
  const int m0 = blockIdx.x * 128;
  const int bn = blockIdx.y;
  const int sel = bn / 6;
  const int nc0 = (bn - sel * 6) * 128;
  const unsigned short* wsrc = wbf + (size_t)sel * 589824;

  f32x4 acc[4][4];
#pragma unroll
  for (int i = 0; i < 4; ++i)
#pragma unroll
    for (int j = 0; j < 4; ++j) acc[i][j] = (f32x4){0.f, 0.f, 0.f, 0.f};

  const int rA = 64 * (w & 1);
  const int rB = 64 * (w >> 1);

  for (int kit = 0; kit < 12; ++kit) {
    int k0 = kit * 64;
    __syncthreads();
    // stage A,B: [128 rows][64 bf16]; chunk-linear = row*8 + cpos, xor swizzle
#pragma unroll
    for (int i = 0; i < 4; ++i) {
      int cl = (w * 4 + i) * 64 + lane;
      int row = cl >> 3, cp = cl & 7, gch = cp ^ (row & 7);
      __builtin_amdgcn_global_load_lds(
          (GCV*)(hidbf + (size_t)(m0 + row) * 768 + k0 + gch * 8),
          (LDSV*)(lda + (size_t)(w * 4 + i) * 512), 16, 0, 0);
      __builtin_amdgcn_global_load_lds(
          (GCV*)(wsrc + (size_t)(nc0 + row) * 768 + k0 + gch * 8),
          (LDSV*)(ldb + (size_t)(w * 4 + i) * 512), 16, 0, 0);
    }
    __syncthreads();

    s16x8 af[4][2], bfr[4][2];
#pragma unroll
    for (int mt = 0; mt < 4; ++mt)
#pragma unroll
      for (int ks = 0; ks < 2; ++ks) {
        int row = rA + 16 * mt + l15;
        af[mt][ks] = *(const s16x8*)(lda + row * 64 + (((quad + 4 * ks) ^ (row & 7)) * 8));
        int rowb = rB + 16 * mt + l15;
        bfr[mt][ks] = *(const s16x8*)(ldb + rowb * 64 + (((quad + 4 * ks) ^ (rowb & 7)) * 8));
      }
#pragma unroll
    for (int mt = 0; mt < 4; ++mt)
#pragma unroll
      for (int nt = 0; nt < 4; ++nt) {
        acc[mt][nt] = MFMA(af[mt][0], bfr[nt][0], acc[mt][nt]);
        acc[mt][nt] = MFMA(af[mt][1], bfr[nt][1], acc[mt][nt]);
      }
  }

  const float* bias = sel == 0 ? bq : (sel == 1 ? bk : bv);
#pragma unroll
  for (int nt = 0; nt < 4; ++nt) {
    int oc = nc0 + rB + 16 * nt + l15;          // [0,768)
    float bvl = bias[oc];
    int h = oc >> 6, dd = oc & 63;
#pragma unroll
    for (int mt = 0; mt < 4; ++mt) {
      int mbase = m0 + rA + 16 * mt + quad * 4;
      int b = mbase >> 10, s = mbase & 1023;
      size_t bh = (size_t)(b * 12 + h);
      if (sel < 2) {
        unsigned short* dst = (sel == 0 ? qb : kb) + bh * 65536 + (size_t)s * 64 + dd;
#pragma unroll
        for (int r = 0; r < 4; ++r) dst[(size_t)r * 64] = f2bf(acc[mt][nt][r] + bvl);
      } else {
        ushort4 pk;
        pk.x = f2bf(acc[mt][nt][0] + bvl); pk.y = f2bf(acc[mt][nt][1] + bvl);
        pk.z = f2bf(acc[mt][nt][2] + bvl); pk.w = f2bf(acc[mt][nt][3] + bvl);
        *(ushort4*)(vtb + bh * 65536 + (size_t)dd * 1024 + s) = pk;
      }
    }
  }
}

// ---------------------------------------------------------------------------
// Kernel 2: fused attention. One block = (bh, 64 q-rows). 4 waves, wave w owns
// i-strip [16w,16w+16). S computed TRANSPOSED (A=k,B=q): lane holds
// St[j=16mt+4q+r][i=l15]. Bias via Qe=q@E^T (per-wave) and Ke=k@E^T (coop),
// sheared through LDS at READ time. Max-free online softmax. PV via P through
// LDS (aliases qet region) as A-frag; V pre-transposed, double-buffered.
// Staging for it+1 issued mid-iter => latency hidden under softmax+PV.
// ---------------------------------------------------------------------------
__global__ __launch_bounds__(256, 2) void attn_kernel(
    const unsigned short* __restrict__ qb, const unsigned short* __restrict__ kb,
    const unsigned short* __restrict__ vtb, const unsigned short* __restrict__ ebf,
    const float* __restrict__ mask, float* __restrict__ out) {
  __shared__ unsigned short ksw[64 * 64];        // 8KB  swizzled
  __shared__ unsigned short vsw[2][64 * 64];     // 16KB swizzled (rows = d), dbuf
  __shared__ unsigned short esw[128 * 64];       // 16KB swizzled (rows = t)
  __shared__ unsigned short keb[128 * 68];       // 17KB Ke[t][j] bf16, stride 68
  __shared__ unsigned short qet[4][80 * 20];     // 12.5KB per-wave Qe^T [t'][i] / P[i][j]
  __shared__ float ml[1024];                     // 4KB  mask row * log2(e)
  // total 73.5KB -> 2 blocks/CU

  const int tid = threadIdx.x;
  const int w = tid >> 6, lane = tid & 63, quad = lane >> 4, l15 = lane & 15;
  const int blk0 = blockIdx.x;
  const int blk = (blk0 & 7) * 96 + (blk0 >> 3);   // XCD-bijective (768 = 8*96):
  const int bh = blk >> 4;                         // all 16 l-tiles of a bh on one XCD
  const int l0 = (blk & 15) << 6;
  const int b = bh / 12;
  const int h = bh - b * 12;

  const float SC1 = 0.18033688f;   // log2(e)/8
  const float SC2 = 1.44269504f;   // log2(e)

  const unsigned short* kbh = kb + (size_t)bh * 65536;
  const unsigned short* vbh = vtb + (size_t)bh * 65536;
  unsigned short* qtw = &qet[w][0];

  // ---- staging helpers (async global->LDS, 16B/lane, xor-swizzled chunks)
  auto stage_k = [&](int r0) {
    const unsigned short* kbase = kbh + (size_t)r0 * 64;
#pragma unroll
    for (int i = 0; i < 2; ++i) {
      int cl = (w * 2 + i) * 64 + lane;
      int row = cl >> 3, cp = cl & 7, gch = cp ^ (row & 7);
      __builtin_amdgcn_global_load_lds((GCV*)(kbase + row * 64 + gch * 8),
                                       (LDSV*)(ksw + (size_t)(w * 2 + i) * 512), 16, 0, 0);
    }
  };
  auto stage_v = [&](int r0, int buf) {
    const unsigned short* vbase = vbh + r0;
#pragma unroll
    for (int i = 0; i < 2; ++i) {
      int cl = (w * 2 + i) * 64 + lane;
      int row = cl >> 3, cp = cl & 7, gch = cp ^ (row & 7);
      __builtin_amdgcn_global_load_lds((GCV*)(vbase + (size_t)row * 1024 + gch * 8),
                                       (LDSV*)(&vsw[buf][0] + (size_t)(w * 2 + i) * 512), 16, 0, 0);
    }
  };
  auto stage_e = [&](int dbase) {
    const unsigned short* ebase = ebf + (size_t)dbase * 64;
#pragma unroll
    for (int i = 0; i < 4; ++i) {
      int cl = (w * 4 + i) * 64 + lane;
      int row = cl >> 3, cp = cl & 7, gch = cp ^ (row & 7);
      __builtin_amdgcn_global_load_lds((GCV*)(ebase + row * 64 + gch * 8),
                                       (LDSV*)(esw + (size_t)(w * 4 + i) * 512), 16, 0, 0);
    }
  };

  // stage mask row (pre-scaled); ordered before first use by loop barriers
  {
    float4 mv = ((const float4*)(mask + (size_t)b * 1024))[tid];
    float4 ms; ms.x = mv.x * SC2; ms.y = mv.y * SC2; ms.z = mv.z * SC2; ms.w = mv.w * SC2;
    ((float4*)ml)[tid] = ms;
  }

  // q B-frags for strip row l0+16w+l15 (held all 16 iters)
  const unsigned short* qrow = qb + (size_t)bh * 65536 + (size_t)(l0 + 16 * w + l15) * 64;
  s16x8 qf[2];
  qf[0] = *(const s16x8*)(qrow + quad * 8);
  qf[1] = *(const s16x8*)(qrow + 32 + quad * 8);

  f32x4 oacc[4];
#pragma unroll
  for (int i = 0; i < 4; ++i) oacc[i] = (f32x4){0.f, 0.f, 0.f, 0.f};
  float lsum = 0.f;

  // ---- prologue: stage tile 0
  stage_k(0);
  stage_e(l0 + 960);
  stage_v(0, 0);

  for (int it = 0; it < 16; ++it) {
    const int r0 = it << 6;
    const int cur = it & 1;
    __syncthreads();   // drains vmcnt -> staged k/E/v[cur] ready; prev phase2 done

    // ---- phase1: k A-frags (feed St and Ke)
    s16x8 kf[4][2];
#pragma unroll
    for (int mt = 0; mt < 4; ++mt)
#pragma unroll
      for (int ks = 0; ks < 2; ++ks) {
        int row = 16 * mt + l15;
        kf[mt][ks] = *(const s16x8*)(ksw + row * 64 + (((quad + 4 * ks) ^ (row & 7)) * 8));
      }

    // ---- St[j][i] = k . q
    f32x4 st[4];
#pragma unroll
    for (int mt = 0; mt < 4; ++mt) {
      f32x4 a = (f32x4){0.f, 0.f, 0.f, 0.f};
      a = MFMA(kf[mt][0], qf[0], a);
      a = MFMA(kf[mt][1], qf[1], a);
      st[mt] = a;
    }

    // ---- Qe (wave window t-tiles [w, w+4]) -> qet[t'=16tp+l15][i=4quad+r]
    // (one b64 write per tile). Ke piggybacks on tp==w, w+1 (wave-uniform).
#pragma unroll
    for (int tp = 0; tp < 5; ++tp) {
      int tt = w + tp;
      int row = 16 * tt + l15;
      s16x8 ef0 = *(const s16x8*)(esw + row * 64 + ((quad ^ (row & 7)) * 8));
      s16x8 ef1 = *(const s16x8*)(esw + row * 64 + (((quad + 4) ^ (row & 7)) * 8));
      f32x4 a = (f32x4){0.f, 0.f, 0.f, 0.f};
      a = MFMA(qf[0], ef0, a);
      a = MFMA(qf[1], ef1, a);
      {
        uint2 pk; pk.x = packbf(a[0], a[1]); pk.y = packbf(a[2], a[3]);
        *(uint2*)(qtw + (16 * tp + l15) * 20 + 4 * quad) = pk;
      }
      if (tp == w || tp == w + 1) {   // this wave owns Ke tiles 2w, 2w+1
#pragma unroll
        for (int mt = 0; mt < 4; ++mt) {
          f32x4 ka = (f32x4){0.f, 0.f, 0.f, 0.f};
          ka = MFMA(kf[mt][0], ef0, ka);
          ka = MFMA(kf[mt][1], ef1, ka);
          int t = 16 * tt + l15;
          int jb = 16 * mt + 4 * quad;
          uint2 pk; pk.x = packbf(ka[0], ka[1]); pk.y = packbf(ka[2], ka[3]);
          *(uint2*)(keb + t * 68 + jb) = pk;
        }
      }
    }
    __syncthreads();   // ksw/esw reads done block-wide; keb/qet visible

    // ---- issue stage for it+1 (drained by NEXT top-of-loop barrier; the
    // whole softmax+PV phase below covers the L2/HBM latency)
    if (it < 15) {
      stage_k(r0 + 64);
      stage_e(l0 - r0 - 64 + 960);
      stage_v(r0 + 64, cur ^ 1);
    }

    // ---- phase2: gather shear + max-free softmax; lane's i = l15
    float pr[4][4];
    const float* mlr = ml + r0;
#pragma unroll
    for (int mt = 0; mt < 4; ++mt) {
      int jb = 16 * mt + 4 * quad;
      float4 mk4 = *(const float4*)(mlr + jb);
#pragma unroll
      for (int r = 0; r < 4; ++r) {
        int j = jb + r;
        int tp_ = l15 - j + 63;          // [0,78]
        float qv = bf2f(qtw[tp_ * 20 + l15]);
        float kv = bf2f(keb[(16 * w + tp_) * 68 + j]);
        float p = exp2f((st[mt][r] + qv + kv) * SC1 + ((const float*)&mk4)[r]);
        pr[mt][r] = p;
        lsum += p;
      }
    }

    // ---- P -> per-wave LDS [i=l15][j] stride 72 (aliases qet region; all
    // gather reads above precede these stores via same-array ordering)
#pragma unroll
    for (int mt = 0; mt < 4; ++mt) {
      uint2 pk; pk.x = packbf(pr[mt][0], pr[mt][1]); pk.y = packbf(pr[mt][2], pr[mt][3]);
      *(uint2*)(qtw + l15 * 72 + 16 * mt + 4 * quad) = pk;
    }
    s16x8 pf0 = *(const s16x8*)(qtw + l15 * 72 + quad * 8);
    s16x8 pf1 = *(const s16x8*)(qtw + l15 * 72 + 32 + quad * 8);

    // ---- O += P @ V  (B-frags from transposed V in LDS, buffer cur)
#pragma unroll
    for (int dt = 0; dt < 4; ++dt) {
      int row = 16 * dt + l15;
      const unsigned short* vb = &vsw[cur][0];
      s16x8 vf0 = *(const s16x8*)(vb + row * 64 + ((quad ^ (row & 7)) * 8));
      s16x8 vf1 = *(const s16x8*)(vb + row * 64 + (((quad + 4) ^ (row & 7)) * 8));
      oacc[dt] = MFMA(pf0, vf0, oacc[dt]);
      oacc[dt] = MFMA(pf1, vf1, oacc[dt]);
    }
  }

  // ---- finalize: row sums live per-lane (i=l15); combine quads, divide, store
  lsum += __shfl_xor(lsum, 16, 64);
  lsum += __shfl_xor(lsum, 32, 64);
#pragma unroll
  for (int r = 0; r < 4; ++r) {
    float ls = __shfl(lsum, quad * 4 + r, 64);
    float rinv = 1.0f / ls;
    int l = l0 + 16 * w + quad * 4 + r;
    float* dst = out + ((size_t)(b * 1024 + l)) * 768 + h * 64;
#pragma unroll
    for (int dt = 0; dt < 4; ++dt) dst[16 * dt + l15] = oacc[dt][r] * rinv;
  }
}

// ---------------------------------------------------------------------------
extern "C" void kernel_launch(void* const* d_in, const int* in_sizes, int n_in,
                              void* d_out, int out_size, void* d_ws, size_t ws_size,
                              hipStream_t stream) {
  const float* hid  = (const float*)d_in[0];
  const float* mask = (const float*)d_in[1];
  const float* wq   = (const float*)d_in[2];
  const float* bq   = (const float*)d_in[3];
  const float* wk   = (const float*)d_in[4];
  const float* bk   = (const float*)d_in[5];
  const float* wv   = (const float*)d_in[6];
  const float* bv   = (const float*)d_in[7];
  const float* de   = (const float*)d_in[8];

  char* ws = (char*)d_ws;
  unsigned short* hidbf = (unsigned short*)(ws);                  // 6,291,456 B
  unsigned short* wbf   = (unsigned short*)(ws + 6291456);        // 3,538,944 B
  unsigned short* ebf   = (unsigned short*)(ws + 9830400);        //   262,144 B
  unsigned short* qb    = (unsigned short*)(ws + 10092544);       // 6,291,456 B
  unsigned short* kb    = (unsigned short*)(ws + 16384000);       // 6,291,456 B
  unsigned short* vtb   = (unsigned short*)(ws + 22675456);       // 6,291,456 B

  convert_kernel<<<4928, 256, 0, stream>>>(hid, wq, wk, wv, de, hidbf, wbf, ebf);
  qkv_gemm<<<dim3(32, 18), 256, 0, stream>>>(hidbf, wbf, bq, bk, bv, qb, kb, vtb);
  attn_kernel<<<768, 256, 0, stream>>>(qb, kb, vtb, ebf, mask, (float*)d_out);
}

// Round 6
// 182.926 us; speedup vs baseline: 1.2222x; 1.0083x over previous
//
#include <hip/hip_runtime.h>
#include <stdint.h>

// ---------------------------------------------------------------------------
// BertSelfAttention (relative_key_query) on gfx950.
// B=4 S=1024 H=768 nH=12 dH=64 MAXPOS=1024.
//   q,k,v = hidden @ W{q,k,v}.T + b        (bf16 MFMA GEMM)
//   S[l,r] = q.k + q.E[l-r+1023] + k.E[l-r+1023];  softmax(S/8 + mask) @ v
// Pipeline: convert(fp32->bf16) -> qkv_gemm -> fused flash attention.
// v7 attn = v6 + shear-at-WRITE (no cvtpk asm; verified-algebra formulas):
//   - Qe/Ke stored sheared [i][j] via predicated scalar stores; softmax
//     gather becomes 8 aligned s16x4 reads (was 32 conflicted scalar).
//   - LDS diet: keb 17K->keS 8.5K, qet 12.5K->qp 9K (Qe/P alias), vsw
//     single-buffered, mask bf16 2K  => 51.5KB -> 3 blocks/CU (grid 768
//     = 256 CU x 3, fully resident), launch_bounds(256,3), VGPR ~90 ok.
//   - pipeline: V(it) staged at top (covered by phase1); K/E(it+1) staged
//     after mid barrier (covered by phase2). Mid barrier drains only V.
//   - s_setprio(1) around MFMA clusters (T5, attn-proven).
// ---------------------------------------------------------------------------

typedef __attribute__((ext_vector_type(4))) float f32x4;
typedef __attribute__((ext_vector_type(8))) short s16x8;
typedef __attribute__((ext_vector_type(4))) short s16x4;
typedef const __attribute__((address_space(1))) void GCV;
typedef __attribute__((address_space(3))) void LDSV;

__device__ __forceinline__ unsigned short f2bf(float f) {
  union { float f; uint32_t u; } v; v.f = f;
  uint32_t r = (v.u + 0x7FFFu + ((v.u >> 16) & 1u)) >> 16;
  return (unsigned short)r;
}
__device__ __forceinline__ float bf2f(unsigned short b) {
  union { uint32_t u; float f; } v; v.u = ((uint32_t)b) << 16;
  return v.f;
}
__device__ __forceinline__ uint32_t packbf(float a, float b) {
  return (uint32_t)f2bf(a) | ((uint32_t)f2bf(b) << 16);
}

#define MFMA(a, b, c) __builtin_amdgcn_mfma_f32_16x16x32_bf16((a), (b), (c), 0, 0, 0)

// ---------------------------------------------------------------------------
// Kernel 0: fp32 -> bf16 conversion. hidden [4096x768], Wq|Wk|Wv [768x768]x3,
// dist_emb [2047x64] padded to 2048 rows (row 2047 = 0).
// ---------------------------------------------------------------------------
#define HIDQ 786432   // 4096*768/4
#define WQ4  147456   // 768*768/4
#define EQ4  32768    // 2048*64/4

__global__ __launch_bounds__(256) void convert_kernel(
    const float* __restrict__ hid, const float* __restrict__ wq,
    const float* __restrict__ wk, const float* __restrict__ wv,
    const float* __restrict__ de,
    unsigned short* __restrict__ hidbf, unsigned short* __restrict__ wbf,
    unsigned short* __restrict__ ebf) {
  int g = blockIdx.x * 256 + threadIdx.x;
  if (g < HIDQ) {
    float4 s = ((const float4*)hid)[g];
    ushort4 o; o.x = f2bf(s.x); o.y = f2bf(s.y); o.z = f2bf(s.z); o.w = f2bf(s.w);
    ((ushort4*)hidbf)[g] = o;
  } else if (g < HIDQ + 3 * WQ4) {
    int r = g - HIDQ;
    int sel = r / WQ4, r2 = r - sel * WQ4;
    const float* src = sel == 0 ? wq : (sel == 1 ? wk : wv);
    float4 s = ((const float4*)src)[r2];
    ushort4 o; o.x = f2bf(s.x); o.y = f2bf(s.y); o.z = f2bf(s.z); o.w = f2bf(s.w);
    ((ushort4*)wbf)[r] = o;
  } else {
    int r = g - HIDQ - 3 * WQ4;      // [0, 32768)
    int e = 4 * r;                   // element index into 2048*64
    ushort4 o;
    o.x = (e + 0 < 131008) ? f2bf(de[e + 0]) : 0;
    o.y = (e + 1 < 131008) ? f2bf(de[e + 1]) : 0;
    o.z = (e + 2 < 131008) ? f2bf(de[e + 2]) : 0;
    o.w = (e + 3 < 131008) ? f2bf(de[e + 3]) : 0;
    ((ushort4*)ebf)[r] = o;
  }
}

// ---------------------------------------------------------------------------
// Kernel 1: QKV projection GEMM.  C[m, o] = sum_i hid[m,i] * W[o,i] + bias[o]
// M=4096, N=2304 (q|k|v), K=768. 128x128 tile, BK=64, 4 waves (64x64 each).
// Outputs: q,k -> [bh][s][64] bf16 ; v -> transposed [bh][d][1024] bf16.
// ---------------------------------------------------------------------------
__global__ __launch_bounds__(256, 2) void qkv_gemm(
    const unsigned short* __restrict__ hidbf,   // [4096][768]
    const unsigned short* __restrict__ wbf,     // [3][768][768]
    const float* __restrict__ bq, const float* __restrict__ bk,
    const float* __restrict__ bv,
    unsigned short* __restrict__ qb, unsigned short* __restrict__ kb,
    unsigned short* __restrict__ vtb) {
  __shared__ unsigned short lda[128 * 64];   // 16KB, xor-swizzled 16B chunks
  __shared__ unsigned short ldb[128 * 64];   // 16KB
  const int tid = threadIdx.x;
  const int w = tid >> 6, lane = tid & 63, quad = lane >> 4, l15 = lane & 15;
  const int m0 = blockIdx.x * 128;
  const int bn = blockIdx.y;
  const int sel = bn / 6;
  const int nc0 = (bn - sel * 6) * 128;
  const unsigned short* wsrc = wbf + (size_t)sel * 589824;

  f32x4 acc[4][4];
#pragma unroll
  for (int i = 0; i < 4; ++i)
#pragma unroll
    for (int j = 0; j < 4; ++j) acc[i][j] = (f32x4){0.f, 0.f, 0.f, 0.f};

  const int rA = 64 * (w & 1);
  const int rB = 64 * (w >> 1);

  for (int kit = 0; kit < 12; ++kit) {
    int k0 = kit * 64;
    __syncthreads();
    // stage A,B: [128 rows][64 bf16]; chunk-linear = row*8 + cpos, xor swizzle
#pragma unroll
    for (int i = 0; i < 4; ++i) {
      int cl = (w * 4 + i) * 64 + lane;
      int row = cl >> 3, cp = cl & 7, gch = cp ^ (row & 7);
      __builtin_amdgcn_global_load_lds(
          (GCV*)(hidbf + (size_t)(m0 + row) * 768 + k0 + gch * 8),
          (LDSV*)(lda + (size_t)(w * 4 + i) * 512), 16, 0, 0);
      __builtin_amdgcn_global_load_lds(
          (GCV*)(wsrc + (size_t)(nc0 + row) * 768 + k0 + gch * 8),
          (LDSV*)(ldb + (size_t)(w * 4 + i) * 512), 16, 0, 0);
    }
    __syncthreads();

    s16x8 af[4][2], bfr[4][2];
#pragma unroll
    for (int mt = 0; mt < 4; ++mt)
#pragma unroll
      for (int ks = 0; ks < 2; ++ks) {
        int row = rA + 16 * mt + l15;
        af[mt][ks] = *(const s16x8*)(lda + row * 64 + (((quad + 4 * ks) ^ (row & 7)) * 8));
        int rowb = rB + 16 * mt + l15;
        bfr[mt][ks] = *(const s16x8*)(ldb + rowb * 64 + (((quad + 4 * ks) ^ (rowb & 7)) * 8));
      }
#pragma unroll
    for (int mt = 0; mt < 4; ++mt)
#pragma unroll
      for (int nt = 0; nt < 4; ++nt) {
        acc[mt][nt] = MFMA(af[mt][0], bfr[nt][0], acc[mt][nt]);
        acc[mt][nt] = MFMA(af[mt][1], bfr[nt][1], acc[mt][nt]);
      }
  }

  const float* bias = sel == 0 ? bq : (sel == 1 ? bk : bv);
#pragma unroll
  for (int nt = 0; nt < 4; ++nt) {
    int oc = nc0 + rB + 16 * nt + l15;          // [0,768)
    float bvl = bias[oc];
    int h = oc >> 6, dd = oc & 63;
#pragma unroll
    for (int mt = 0; mt < 4; ++mt) {
      int mbase = m0 + rA + 16 * mt + quad * 4;
      int b = mbase >> 10, s = mbase & 1023;
      size_t bh = (size_t)(b * 12 + h);
      if (sel < 2) {
        unsigned short* dst = (sel == 0 ? qb : kb) + bh * 65536 + (size_t)s * 64 + dd;
#pragma unroll
        for (int r = 0; r < 4; ++r) dst[(size_t)r * 64] = f2bf(acc[mt][nt][r] + bvl);
      } else {
        ushort4 pk;
        pk.x = f2bf(acc[mt][nt][0] + bvl); pk.y = f2bf(acc[mt][nt][1] + bvl);
        pk.z = f2bf(acc[mt][nt][2] + bvl); pk.w = f2bf(acc[mt][nt][3] + bvl);
        *(ushort4*)(vtb + bh * 65536 + (size_t)dd * 1024 + s) = pk;
      }
    }
  }
}

// ---------------------------------------------------------------------------
// Kernel 2: fused attention. One block = (bh, 64 q-rows). 4 waves, wave w owns
// i-strip [16w,16w+16). S computed TRANSPOSED (A=k,B=q): lane holds
// St[j=16mt+4q+r][i=l15]. Bias GEMMs Qe=q@E^T (per-wave) and Ke=k@E^T (coop)
// store SHEARED [i][j] so the softmax gather is aligned s16x4. Max-free
// online softmax. PV via P through per-wave LDS (aliases Qe region).
// ---------------------------------------------------------------------------
__global__ __launch_bounds__(256, 3) void attn_kernel(
    const unsigned short* __restrict__ qb, const unsigned short* __restrict__ kb,
    const unsigned short* __restrict__ vtb, const unsigned short* __restrict__ ebf,
    const float* __restrict__ mask, float* __restrict__ out) {
  __shared__ unsigned short ksw[64 * 64];        // 8KB   swizzled
  __shared__ unsigned short vsw[64 * 64];        // 8KB   swizzled (rows = d)
  __shared__ unsigned short esw[128 * 64];       // 16KB  swizzled (rows = t)
  __shared__ unsigned short keS[64 * 68];        // 8.5KB sheared Ke[i][j], stride 68
  __shared__ unsigned short qp[4][16 * 72];      // 9KB   per-wave sheared Qe[i][j] / P[i][j]
  __shared__ unsigned short mlb[1024];           // 2KB   mask row * log2(e), bf16
  // total 51.5KB -> 3 blocks/CU

  const int tid = threadIdx.x;
  const int w = tid >> 6, lane = tid & 63, quad = lane >> 4, l15 = lane & 15;
  const int blk0 = blockIdx.x;
  const int blk = (blk0 & 7) * 96 + (blk0 >> 3);   // XCD-bijective (768 = 8*96):
  const int bh = blk >> 4;                         // all 16 l-tiles of a bh on one XCD
  const int l0 = (blk & 15) << 6;
  const int b = bh / 12;
  const int h = bh - b * 12;

  const float SC1 = 0.18033688f;   // log2(e)/8
  const float SC2 = 1.44269504f;   // log2(e)

  const unsigned short* kbh = kb + (size_t)bh * 65536;
  const unsigned short* vbh = vtb + (size_t)bh * 65536;
  unsigned short* qpw = &qp[w][0];

  // ---- staging helpers (async global->LDS, 16B/lane, xor-swizzled chunks)
  auto stage_k = [&](int r0) {
    const unsigned short* kbase = kbh + (size_t)r0 * 64;
#pragma unroll
    for (int i = 0; i < 2; ++i) {
      int cl = (w * 2 + i) * 64 + lane;
      int row = cl >> 3, cp = cl & 7, gch = cp ^ (row & 7);
      __builtin_amdgcn_global_load_lds((GCV*)(kbase + row * 64 + gch * 8),
                                       (LDSV*)(ksw + (size_t)(w * 2 + i) * 512), 16, 0, 0);
    }
  };
  auto stage_v = [&](int r0) {
    const unsigned short* vbase = vbh + r0;
#pragma unroll
    for (int i = 0; i < 2; ++i) {
      int cl = (w * 2 + i) * 64 + lane;
      int row = cl >> 3, cp = cl & 7, gch = cp ^ (row & 7);
      __builtin_amdgcn_global_load_lds((GCV*)(vbase + (size_t)row * 1024 + gch * 8),
                                       (LDSV*)(vsw + (size_t)(w * 2 + i) * 512), 16, 0, 0);
    }
  };
  auto stage_e = [&](int dbase) {
    const unsigned short* ebase = ebf + (size_t)dbase * 64;
#pragma unroll
    for (int i = 0; i < 4; ++i) {
      int cl = (w * 4 + i) * 64 + lane;
      int row = cl >> 3, cp = cl & 7, gch = cp ^ (row & 7);
      __builtin_amdgcn_global_load_lds((GCV*)(ebase + row * 64 + gch * 8),
                                       (LDSV*)(esw + (size_t)(w * 4 + i) * 512), 16, 0, 0);
    }
  };

  // stage mask row (pre-scaled by log2e, bf16); ordered by first top barrier
  {
    float4 mv = ((const float4*)(mask + (size_t)b * 1024))[tid];
    ushort4 ms;
    ms.x = f2bf(mv.x * SC2); ms.y = f2bf(mv.y * SC2);
    ms.z = f2bf(mv.z * SC2); ms.w = f2bf(mv.w * SC2);
    *(ushort4*)(mlb + tid * 4) = ms;
  }

  // q B-frags for strip row l0+16w+l15 (held all 16 iters)
  const unsigned short* qrow = qb + (size_t)bh * 65536 + (size_t)(l0 + 16 * w + l15) * 64;
  s16x8 qf[2];
  qf[0] = *(const s16x8*)(qrow + quad * 8);
  qf[1] = *(const s16x8*)(qrow + 32 + quad * 8);

  f32x4 oacc[4];
#pragma unroll
  for (int i = 0; i < 4; ++i) oacc[i] = (f32x4){0.f, 0.f, 0.f, 0.f};
  float lsum = 0.f;

  // ---- prologue: stage k/E for it=0
  stage_k(0);
  stage_e(l0 + 960);

  for (int it = 0; it < 16; ++it) {
    const int r0 = it << 6;
    __syncthreads();   // top: k/E(it) ready (vmcnt drain); all prev-iter PV reads done
    stage_v(r0);       // into single-buffer vsw; latency covered by phase1

    // ---- phase1: k A-frags (feed St and Ke)
    s16x8 kf[4][2];
#pragma unroll
    for (int mt = 0; mt < 4; ++mt)
#pragma unroll
      for (int ks = 0; ks < 2; ++ks) {
        int row = 16 * mt + l15;
        kf[mt][ks] = *(const s16x8*)(ksw + row * 64 + (((quad + 4 * ks) ^ (row & 7)) * 8));
      }

    // ---- St[j][i] = k . q
    __builtin_amdgcn_s_setprio(1);
    f32x4 st[4];
#pragma unroll
    for (int mt = 0; mt < 4; ++mt) {
      f32x4 a = (f32x4){0.f, 0.f, 0.f, 0.f};
      a = MFMA(kf[mt][0], qf[0], a);
      a = MFMA(kf[mt][1], qf[1], a);
      st[mt] = a;
    }
    __builtin_amdgcn_s_setprio(0);

    // ---- Qe (wave window t-tiles [w, w+4]): a[r] is Qe at
    //   (i_local = 4*quad + r, t = 16*(w+tp) + l15);  sheared col
    //   j = i + 63 - t = (4*quad + r) + 63 - 16*tp - l15   (w cancels).
    // Ke piggybacks on tp==w, w+1 (wave-uniform; tiles tt = 2w, 2w+1):
    //   ka[r] is Ke at (t = 16*tt + l15, j = 16*mt + 4*quad + r);
    //   sheared row i = t + j - 63.
#pragma unroll
    for (int tp = 0; tp < 5; ++tp) {
      int tt = w + tp;
      int row = 16 * tt + l15;
      s16x8 ef0 = *(const s16x8*)(esw + row * 64 + ((quad ^ (row & 7)) * 8));
      s16x8 ef1 = *(const s16x8*)(esw + row * 64 + (((quad + 4) ^ (row & 7)) * 8));
      __builtin_amdgcn_s_setprio(1);
      f32x4 a = (f32x4){0.f, 0.f, 0.f, 0.f};
      a = MFMA(qf[0], ef0, a);
      a = MFMA(qf[1], ef1, a);
      __builtin_amdgcn_s_setprio(0);
#pragma unroll
      for (int r = 0; r < 4; ++r) {
        int j = 4 * quad + r + 63 - 16 * tp - l15;
        if ((unsigned)j < 64u) qpw[(4 * quad + r) * 72 + j] = f2bf(a[r]);
      }
      if (tp == w || tp == w + 1) {
        __builtin_amdgcn_s_setprio(1);
        f32x4 ka[4];
#pragma unroll
        for (int mt = 0; mt < 4; ++mt) {
          f32x4 kacc = (f32x4){0.f, 0.f, 0.f, 0.f};
          kacc = MFMA(kf[mt][0], ef0, kacc);
          kacc = MFMA(kf[mt][1], ef1, kacc);
          ka[mt] = kacc;
        }
        __builtin_amdgcn_s_setprio(0);
#pragma unroll
        for (int mt = 0; mt < 4; ++mt) {
          int jb = 16 * mt + 4 * quad;
          int ib0 = 16 * tt + l15 + jb - 63;
#pragma unroll
          for (int r = 0; r < 4; ++r) {
            int ii = ib0 + r;
            if ((unsigned)ii < 64u) keS[ii * 68 + jb + r] = f2bf(ka[mt][r]);
          }
        }
      }
    }
    __syncthreads();   // mid: drains vmcnt (vsw ready); keS/qp visible block-wide

    // ---- issue stage k/E for it+1 (drained at next top barrier; phase2
    // below covers the latency)
    if (it < 15) {
      stage_k(r0 + 64);
      stage_e(l0 - r0 - 64 + 960);
    }

    // ---- phase2: softmax — sheared bias rows are plain [i][j]: aligned s16x4
    float pr[4][4];
#pragma unroll
    for (int mt = 0; mt < 4; ++mt) {
      int jb = 16 * mt + 4 * quad;
      s16x4 qv4 = *(const s16x4*)(qpw + l15 * 72 + jb);
      s16x4 kv4 = *(const s16x4*)(keS + (16 * w + l15) * 68 + jb);
      s16x4 mk4 = *(const s16x4*)(mlb + r0 + jb);
#pragma unroll
      for (int r = 0; r < 4; ++r) {
        float bias = bf2f((unsigned short)qv4[r]) + bf2f((unsigned short)kv4[r]);
        float p = exp2f((st[mt][r] + bias) * SC1 + bf2f((unsigned short)mk4[r]));
        pr[mt][r] = p;
        lsum += p;
      }
    }

    // ---- P -> per-wave LDS [i=l15][j] (b64 stores; same cells the thread
    // just read as qv4 -> per-thread RAW order holds), then A-frags
#pragma unroll
    for (int mt = 0; mt < 4; ++mt) {
      uint2 pk; pk.x = packbf(pr[mt][0], pr[mt][1]); pk.y = packbf(pr[mt][2], pr[mt][3]);
      *(uint2*)(qpw + l15 * 72 + 16 * mt + 4 * quad) = pk;
    }
    s16x8 pf0 = *(const s16x8*)(qpw + l15 * 72 + quad * 8);
    s16x8 pf1 = *(const s16x8*)(qpw + l15 * 72 + 32 + quad * 8);

    // ---- O += P @ V  (B-frags from transposed V in LDS)
    __builtin_amdgcn_s_setprio(1);
#pragma unroll
    for (int dt = 0; dt < 4; ++dt) {
      int row = 16 * dt + l15;
      s16x8 vf0 = *(const s16x8*)(vsw + row * 64 + ((quad ^ (row & 7)) * 8));
      s16x8 vf1 = *(const s16x8*)(vsw + row * 64 + (((quad + 4) ^ (row & 7)) * 8));
      oacc[dt] = MFMA(pf0, vf0, oacc[dt]);
      oacc[dt] = MFMA(pf1, vf1, oacc[dt]);
    }
    __builtin_amdgcn_s_setprio(0);
  }

  // ---- finalize: row sums live per-lane (i=l15); combine quads, divide, store
  lsum += __shfl_xor(lsum, 16, 64);
  lsum += __shfl_xor(lsum, 32, 64);
#pragma unroll
  for (int r = 0; r < 4; ++r) {
    float ls = __shfl(lsum, quad * 4 + r, 64);
    float rinv = 1.0f / ls;
    int l = l0 + 16 * w + quad * 4 + r;
    float* dst = out + ((size_t)(b * 1024 + l)) * 768 + h * 64;
#pragma unroll
    for (int dt = 0; dt < 4; ++dt) dst[16 * dt + l15] = oacc[dt][r] * rinv;
  }
}

// ---------------------------------------------------------------------------
extern "C" void kernel_launch(void* const* d_in, const int* in_sizes, int n_in,
                              void* d_out, int out_size, void* d_ws, size_t ws_size,
                              hipStream_t stream) {
  const float* hid  = (const float*)d_in[0];
  const float* mask = (const float*)d_in[1];
  const float* wq   = (const float*)d_in[2];
  const float* bq   = (const float*)d_in[3];
  const float* wk   = (const float*)d_in[4];
  const float* bk   = (const float*)d_in[5];
  const float* wv   = (const float*)d_in[6];
  const float* bv   = (const float*)d_in[7];
  const float* de   = (const float*)d_in[8];

  char* ws = (char*)d_ws;
  unsigned short* hidbf = (unsigned short*)(ws);                  // 6,291,456 B
  unsigned short* wbf   = (unsigned short*)(ws + 6291456);        // 3,538,944 B
  unsigned short* ebf   = (unsigned short*)(ws + 9830400);        //   262,144 B
  unsigned short* qb    = (unsigned short*)(ws + 10092544);       // 6,291,456 B
  unsigned short* kb    = (unsigned short*)(ws + 16384000);       // 6,291,456 B
  unsigned short* vtb   = (unsigned short*)(ws + 22675456);       // 6,291,456 B

  convert_kernel<<<4928, 256, 0, stream>>>(hid, wq, wk, wv, de, hidbf, wbf, ebf);
  qkv_gemm<<<dim3(32, 18), 256, 0, stream>>>(hidbf, wbf, bq, bk, bv, qb, kb, vtb);
  attn_kernel<<<768, 256, 0, stream>>>(qb, kb, vtb, ebf, mask, (float*)d_out);
}